// Round 7
// baseline (278.356 us; speedup 1.0000x reference)
//
#include <hip/hip_runtime.h>
#include <hip/hip_bf16.h>

// QuantizedLinear: out[n][o] = scale[o] * dot(x[n,:], (q[o,:]-8)) + bias[o]
// R12 = R10 (flatmm: B global->VGPR fragment-flat, LDS = A only 2x32KB
// double buffer, one vmcnt(4)+barrier per K-tile; 131us) with the MFMA
// shape swapped 16x16x32 -> 32x32x16. Rationale: five schedule variants
// (R6..R11) all pinned at 43-45% MfmaUtil; the 16x16 shape's measured
// ceiling is 2075 TF (83% of peak) vs 32x32's 2495 TF (99.8%, m119) ->
// pipe demand per K-tile drops 2484 -> 2065 cyc, and MFMA count halves
// (longer uninterrupted pipe occupancy per cluster). A staging path
// byte-identical to R10 (chunk-XOR swizzle, pre-swizzled global source,
// linear gload_lds dest). New for the shape: A frag row=lane&31,
// k=(lane>>5)*8+j (offsets re-derived, same swizzle algebra); prep emits
// wb in 32-col-panel fragment-flat order; epilogue uses the VERIFIED
// 32x32 C/D map col=lane&31, row=(reg&3)+8*(reg>>2)+4*(lane>>5) (m74/m101).
// acc = 8 x f32x16 = 128 AGPR (unchanged total), arch VGPR ~110 -> 2
// waves/SIMD preserved.

typedef __attribute__((ext_vector_type(8))) __bf16 bf16x8;
typedef __attribute__((ext_vector_type(16))) float f32x16;

#define GLOBAL_AS __attribute__((address_space(1)))
#define LDS_AS __attribute__((address_space(3)))

#define BM 256
#define BN 256
#define BK 64

__device__ inline unsigned short f32_to_bf16(float f) {
    unsigned int u = __float_as_uint(f);
    unsigned int r = (u + 0x7FFFu + ((u >> 16) & 1u)) >> 16;
    return (unsigned short)r;
}

// ---- preprocessing ----
// x: fp32 -> bf16 linear (unchanged).
// w: packed nibbles -> bf16 in 32x32x16 FRAGMENT-FLAT layout:
//   uint4 index = panel(o>>5)*16384 + (t(k>>6)*4 + s((k>>4)&3))*64
//                 + h((k>>3)&1)*32 + (o&31)        [8 bf16 per uint4, k&7]
// i.e. B-frag lane l = h*32 + col(o&31), elems k = s*16 + h*8 + j.
__global__ void prep(const float* __restrict__ x, unsigned short* __restrict__ xb,
                     const int* __restrict__ wp, unsigned short* __restrict__ wb,
                     int n8x, int n4w) {
    const int stride = gridDim.x * blockDim.x;
    const int total = n8x + n4w;
    for (int i = blockIdx.x * blockDim.x + threadIdx.x; i < total; i += stride) {
        if (i < n8x) {
            float4 a = ((const float4*)x)[2 * i];
            float4 b = ((const float4*)x)[2 * i + 1];
            union { unsigned short h[8]; uint4 u; } o;
            o.h[0] = f32_to_bf16(a.x); o.h[1] = f32_to_bf16(a.y);
            o.h[2] = f32_to_bf16(a.z); o.h[3] = f32_to_bf16(a.w);
            o.h[4] = f32_to_bf16(b.x); o.h[5] = f32_to_bf16(b.y);
            o.h[6] = f32_to_bf16(b.z); o.h[7] = f32_to_bf16(b.w);
            ((uint4*)xb)[i] = o.u;
        } else {
            const int li = i - n8x;          // wave-coherent (n8x = 2^21)
            const int l  = li & 63;
            const int W  = li >> 6;
            const int jb = W >> 7;           // 16-row panel of o
            const int gb = W & 127;
            const int am = l & 15, g4 = l >> 4;
            const int o_ = jb * 16 + am;     // output col 0..4095
            const int g  = gb * 4 + g4;      // 8-k group 0..511 (k = 8g..8g+7)
            int4 v = ((const int4*)wp)[(size_t)o_ * 512 + g];
            int vals[4] = {v.x, v.y, v.z, v.w};
            union { unsigned short h[8]; uint4 u; } u8;
#pragma unroll
            for (int t2 = 0; t2 < 4; ++t2) {
                u8.h[2 * t2]     = f32_to_bf16((float)((vals[t2] & 0xF) - 8));
                u8.h[2 * t2 + 1] = f32_to_bf16((float)(((vals[t2] >> 4) & 0xF) - 8));
            }
            const int p_ = o_ >> 5;          // 32-col panel
            const int t_ = g >> 3;           // K-tile
            const int s_ = (g >> 1) & 3;     // kk-step (K=16) in tile
            const int h_ = g & 1;            // k-half in step
            ((uint4*)wb)[(p_ << 14) | (((t_ << 2) | s_) << 6) | (h_ << 5) | (o_ & 31)] = u8.u;
        }
    }
}

// ---- main GEMM: C[m][n] = sum_k A[m][k]*B[n][k]; epilogue scale/bias ----
// 256x256 tile, 8 waves (wm=wave>>2, wn=wave&3). Per-wave output 128x64 as
// 4x2 tiles of 32x32. LDS = A only: buf0 @ ushort 0, buf1 @ 16384;
// halves (rows 0-127 / 128-255) at +0/+8192 within a buffer.
template<int K, int N>
__global__ __launch_bounds__(512, 2) void gemm_bt(
    const unsigned short* __restrict__ A,
    const unsigned short* __restrict__ Bf,   // fragment-flat layout
    const float* __restrict__ scales,
    const float* __restrict__ bias,
    float* __restrict__ C,
    int GY)
{
    constexpr int NT = K / BK;   // 64 K-tiles
    __shared__ __align__(16) unsigned short lds[32768];  // 64 KiB, A only

    const int tid  = threadIdx.x;
    const int wave = tid >> 6;
    const int lane = tid & 63;
    const int wm = wave >> 2;    // 0..1
    const int wn = wave & 3;     // 0..3

    // XCD swizzle: XCD x = bid&7 owns a 2-column stripe of the 16x16 grid.
    const int bid = blockIdx.x;
    const int chunk = gridDim.x >> 3;
    const int sw = (bid & 7) * chunk + (bid >> 3);
    const int bx = sw / GY;
    const int by = sw - bx * GY;
    const int m0 = by * BM;
    const int n0 = bx * BN;

    // A fragment LDS byte offsets (32x32x16: row = lane&31, k-half = lane>>5)
    const int l31 = lane & 31;
    const int kh  = lane >> 5;   // 0..1
    int aoff32[4][4];            // [mi][s]
#pragma unroll
    for (int mi = 0; mi < 4; ++mi) {
        const int b  = 2 * mi + wm;             // 32-row block 0..7
        const int hr = (b & 3) * 32 + l31;      // row within half 0..127
        const int hbase = (b >> 2) * 16384;     // half region byte offset
#pragma unroll
        for (int s = 0; s < 4; ++s) {
            const int c0 = s * 2 + kh;          // 16B chunk 0..7
            aoff32[mi][s] = hbase + hr * 128 + (((c0 ^ (hr & 7))) << 4);
        }
    }

    // B flat panel bases (ushort units): wave's 32-col panels are wn*2+nj
    int bpan[2];
#pragma unroll
    for (int nj = 0; nj < 2; ++nj)
        bpan[nj] = ((n0 >> 5) + wn * 2 + nj) << 17;
    const int lane8 = lane * 8;

    // A staging: identical to R10. half-tile 128x64 = 1024 16B-chunks;
    // thread covers chunks tid and 512+tid; LDS dest linear, source
    // pre-swizzled by row&7.
    const int sch = tid & 7;
    const int r0 = tid >> 3;
    const int r1 = (512 + tid) >> 3;
    const size_t g0 = (size_t)r0 * K + (size_t)((sch ^ (r0 & 7)) * 8);
    const size_t g1 = (size_t)r1 * K + (size_t)((sch ^ (r1 & 7)) * 8);
    const int d0 = tid * 8;
    const int d1 = (512 + tid) * 8;

    const unsigned short* Abase = A + (size_t)m0 * K;

    f32x16 acc[4][2];
#pragma unroll
    for (int mi = 0; mi < 4; ++mi)
#pragma unroll
        for (int nj = 0; nj < 2; ++nj)
#pragma unroll
            for (int r = 0; r < 16; ++r)
                acc[mi][nj][r] = 0.f;

    const char* ldsB = (const char*)lds;
    bf16x8 af8[8];        // [mi*2+ss] for current K-half (32 VGPR)
    bf16x8 bX[4], bY[4];  // [nj*2+ss] K-half0 / K-half1 (16+16 VGPR)

#define STAGE(half, kcol, uoff)                                                   \
    do {                                                                          \
        const unsigned short* _g = Abase + (size_t)((half) * 128) * K + (kcol);   \
        __builtin_amdgcn_global_load_lds((const GLOBAL_AS void*)(_g + g0),        \
            (LDS_AS void*)(lds + (uoff) + d0), 16, 0, 0);                         \
        __builtin_amdgcn_global_load_lds((const GLOBAL_AS void*)(_g + g1),        \
            (LDS_AS void*)(lds + (uoff) + d1), 16, 0, 0);                         \
    } while (0)

// read A frags for K-half H (s = 2H, 2H+1): 8 x ds_read_b128
#define LDA32(H, OBb)                                                             \
    _Pragma("unroll") for (int mi = 0; mi < 4; ++mi)                              \
    _Pragma("unroll") for (int ss = 0; ss < 2; ++ss)                              \
        af8[mi * 2 + ss] =                                                        \
            *(const bf16x8*)(ldsB + (OBb) + aoff32[mi][(H) * 2 + ss]);

// load B frags for tile TT2, K-half H: 4 x global_load_dwordx4
#define LDBG(dst, TT2, H)                                                         \
    _Pragma("unroll") for (int nj = 0; nj < 2; ++nj)                              \
    _Pragma("unroll") for (int ss = 0; ss < 2; ++ss)                              \
        dst[nj * 2 + ss] = *(const bf16x8*)(Bf + bpan[nj]                         \
            + ((((TT2) << 2) | ((H) << 1) | ss) << 9) + lane8);

// 16 MFMA (4 mi x 2 nj x 2 ss); ss outer so 8 independent updates sit
// between dependent same-acc pairs.
#define MFMA_H(bset)                                                              \
    _Pragma("unroll") for (int ss = 0; ss < 2; ++ss)                              \
    _Pragma("unroll") for (int mi = 0; mi < 4; ++mi)                              \
    _Pragma("unroll") for (int nj = 0; nj < 2; ++nj)                              \
        acc[mi][nj] = __builtin_amdgcn_mfma_f32_32x32x16_bf16(                    \
            af8[mi * 2 + ss], bset[nj * 2 + ss], acc[mi][nj], 0, 0, 0);

// One K-tile (R10 skeleton): vmcnt(4) drains the A(t) staging (oldest 4 VMEM)
// while the 4 newest (bX of this tile or staging in flight) stay counted.
#define TILE(TT, OBb, OUSo)                                                       \
    {                                                                             \
        const int tn = (((TT) + 1 < NT) ? (TT) + 1 : NT - 1);                     \
        asm volatile("s_waitcnt vmcnt(4)" ::: "memory");                          \
        __builtin_amdgcn_s_barrier();                                             \
        LDBG(bY, (TT), 1);                   /* B(t, K-half1), used in ph2 */     \
        STAGE(0, tn * BK, (OUSo));           /* A(t+1) -> other buf */            \
        STAGE(1, tn * BK, (OUSo) + 8192);                                         \
        LDA32(0, OBb);                       /* A K-half0: 8 reads */             \
        __builtin_amdgcn_s_setprio(1); MFMA_H(bX); __builtin_amdgcn_s_setprio(0); \
        LDBG(bX, tn, 0);                     /* B(t+1, K-half0) prefetch */       \
        LDA32(1, OBb);                       /* A K-half1: 8 reads */             \
        __builtin_amdgcn_s_setprio(1); MFMA_H(bY); __builtin_amdgcn_s_setprio(0); \
    }

    // prologue: A(0) -> buf0, B(0, K-half0) -> bX
    STAGE(0, 0, 0);
    STAGE(1, 0, 8192);
    LDBG(bX, 0, 0);

    for (int t = 0; t < NT; t += 2) {
        TILE(t, 0, 16384);
        TILE(t + 1, 32768, 0);
    }
    asm volatile("s_waitcnt vmcnt(0)" ::: "memory");  // drain tail loads

    // epilogue: 32x32 C/D layout col=lane&31, row=(reg&3)+8*(reg>>2)+4*(lane>>5)
#pragma unroll
    for (int nj = 0; nj < 2; ++nj) {
        const int col = n0 + wn * 64 + nj * 32 + l31;
        const float s = scales[col];
        const float b = bias[col];
#pragma unroll
        for (int mi = 0; mi < 4; ++mi) {
            const int rowb = m0 + (2 * mi + wm) * 32 + 4 * kh;
#pragma unroll
            for (int r = 0; r < 16; ++r) {
                const int row = rowb + (r & 3) + 8 * (r >> 2);
                C[(size_t)row * N + col] = acc[mi][nj][r] * s + b;
            }
        }
    }
#undef STAGE
#undef LDA32
#undef LDBG
#undef MFMA_H
#undef TILE
}

// ---- correctness fallback for unexpected shapes ----
__global__ void naive_kernel(const float* __restrict__ x, const int* __restrict__ wp,
                             const float* __restrict__ sc, const float* __restrict__ bs,
                             float* __restrict__ out, int NR, int OUTF, int INF) {
    int idx = blockIdx.x * 256 + threadIdx.x;
    if (idx >= NR * OUTF) return;
    int n = idx / OUTF, o = idx - n * OUTF;
    const float* xr = x + (size_t)n * INF;
    const int* wr = wp + (size_t)o * (INF / 2);
    float acc = 0.f;
    for (int c = 0; c < INF / 2; ++c) {
        int v = wr[c];
        acc += xr[2 * c] * (float)((v & 0xF) - 8) + xr[2 * c + 1] * (float)(((v >> 4) & 0xF) - 8);
    }
    out[idx] = acc * sc[o] + bs[o];
}

extern "C" void kernel_launch(void* const* d_in, const int* in_sizes, int n_in,
                              void* d_out, int out_size, void* d_ws, size_t ws_size,
                              hipStream_t stream) {
    const float* x      = (const float*)d_in[0];
    const int*   wp     = (const int*)d_in[1];
    const float* scales = (const float*)d_in[2];
    const float* bias   = (const float*)d_in[3];
    float* out = (float*)d_out;

    const int OUTF = in_sizes[2];
    const int INF  = (2 * in_sizes[1]) / OUTF;
    const int NR   = in_sizes[0] / INF;

    unsigned short* xb = (unsigned short*)d_ws;
    unsigned short* wb = xb + (size_t)NR * INF;
    const size_t need = ((size_t)NR * INF + (size_t)OUTF * INF) * sizeof(unsigned short);

    const int GX = OUTF / BN;
    const int GY = NR / BM;

    if (ws_size >= need && INF == 4096 && OUTF == 4096 && NR == 4096
        && ((GX * GY) % 8) == 0
        && (in_sizes[0] % 8) == 0 && (in_sizes[1] % 4) == 0) {
        prep<<<2048, 256, 0, stream>>>(x, xb, wp, wb, in_sizes[0] / 8, in_sizes[1] / 4);
        gemm_bt<4096, 4096><<<GX * GY, 512, 0, stream>>>(xb, wb, scales, bias, out, GY);
    } else {
        int total = NR * OUTF;
        naive_kernel<<<(total + 255) / 256, 256, 0, stream>>>(x, wp, scales, bias, out, NR, OUTF, INF);
    }
}